// Round 7
// baseline (183.530 us; speedup 1.0000x reference)
//
#include <hip/hip_runtime.h>
#include <hip/hip_bf16.h>

#define TSEQ 4096
#define DE   1024
#define NH   16
#define DH   64
#define LD3  3072
#define NCH  64          // chunks of 64 rows for the linear-attention scan

typedef float4 f4;
typedef unsigned short u16;
typedef __attribute__((ext_vector_type(8))) short s16x8;   // 8 bf16 MFMA A/B frag
typedef __attribute__((ext_vector_type(4))) float f32x4;   // MFMA C/D frag

__device__ inline u16 f2bf(float f) {
    unsigned int u = __float_as_uint(f);
    u += 0x7FFF + ((u >> 16) & 1);
    return (u16)(u >> 16);
}

__device__ inline void gl_lds16(const void* g, void* l) {
    __builtin_amdgcn_global_load_lds(
        (const __attribute__((address_space(1))) void*)g,
        (__attribute__((address_space(3))) void*)l, 16, 0, 0);
}

// ---------------- fused prep: cast x -> xb; W1 -> W1t; W2 -> W2t ----------------
__global__ __launch_bounds__(256) void prep_kernel(
    const float* __restrict__ x, const float* __restrict__ W1,
    const float* __restrict__ W2, u16* __restrict__ xb,
    u16* __restrict__ W1t, u16* __restrict__ W2t) {
    __shared__ u16 Ts[64][65];
    const int b = blockIdx.x, tid = threadIdx.x;

    if (b < 4096) {   // cast x
        int i = b * 256 + tid;
        f4 v = *reinterpret_cast<const f4*>(&x[(size_t)i * 4]);
        ushort4 o = make_ushort4(f2bf(v.x), f2bf(v.y), f2bf(v.z), f2bf(v.w));
        *reinterpret_cast<ushort4*>(&xb[(size_t)i * 4]) = o;
        return;
    }
    const float* in; u16* out; int in_ld, out_ld, r0, c0;
    if (b < 4864) {
        int i = b - 4096;
        in = W1; out = W1t; in_ld = LD3; out_ld = DE;
        r0 = (i / 48) * 64; c0 = (i % 48) * 64;
    } else {
        int i = b - 4864;
        in = W2; out = W2t; in_ld = DE; out_ld = DE;
        r0 = (i / 16) * 64; c0 = (i % 16) * 64;
    }
    #pragma unroll
    for (int l = 0; l < 4; ++l) {
        int f = tid + 256 * l, r = f >> 4, c = (f & 15) * 4;
        f4 v = *reinterpret_cast<const f4*>(&in[(size_t)(r0 + r) * in_ld + c0 + c]);
        Ts[c + 0][r] = f2bf(v.x); Ts[c + 1][r] = f2bf(v.y);
        Ts[c + 2][r] = f2bf(v.z); Ts[c + 3][r] = f2bf(v.w);
    }
    __syncthreads();
    #pragma unroll
    for (int l = 0; l < 2; ++l) {
        int f = tid + 256 * l, r2 = f >> 3, c2 = (f & 7) * 8;
        union { u16 u[8]; f4 v; } pk;
        #pragma unroll
        for (int j = 0; j < 8; ++j) pk.u[j] = Ts[r2][c2 + j];
        *reinterpret_cast<f4*>(&out[(size_t)(c0 + r2) * out_ld + r0 + c2]) = pk.v;
    }
}

// ---------------- bf16 MFMA GEMM, BK=64, tile TM x 128 ----------------
// C[M][N] = A[M][K] @ Bt[N][K]^T + bias. 256 threads, 4 waves in 2x2,
// wave tile (TM/2) x 64. gl_lds16: one wave-issue = 8 rows (64 lanes x 16B).
// Accumulation order identical to BK=32 version (bit-identical results).
template<int TM, bool OUT_BF16>
__global__ __launch_bounds__(256) void gemm_mfma(
    const u16* __restrict__ A, const u16* __restrict__ Bt,
    const float* __restrict__ bias, void* __restrict__ Cout,
    int M, int N, int K) {
    constexpr int MT = TM / 32;          // m sub-tiles per wave
    __shared__ u16 As[TM][64];
    __shared__ u16 Bs[128][64];
    const int tid = threadIdx.x;
    const int m0 = blockIdx.y * TM, n0 = blockIdx.x * 128;
    const int w = tid >> 6, lid = tid & 63, ln = tid & 15, quad = (tid & 63) >> 4;
    const int wm = (w >> 1) * (TM / 2), wn = (w & 1) * 64;
    const int srow = lid >> 3, scol = (lid & 7) * 8;   // lane's slot in an 8-row chunk

    f32x4 acc[MT][4];
    #pragma unroll
    for (int i = 0; i < MT; ++i)
        #pragma unroll
        for (int j = 0; j < 4; ++j) acc[i][j] = 0.f;

    for (int k0 = 0; k0 < K; k0 += 64) {
        __syncthreads();   // previous iteration's readers done
        #pragma unroll
        for (int i = 0; i < TM / 32; ++i) {
            const int rb = i * 32 + w * 8;
            gl_lds16(&A[(size_t)(m0 + rb + srow) * K + k0 + scol], &As[rb][0]);
        }
        #pragma unroll
        for (int i = 0; i < 4; ++i) {
            const int rb = i * 32 + w * 8;
            gl_lds16(&Bt[(size_t)(n0 + rb + srow) * K + k0 + scol], &Bs[rb][0]);
        }
        __syncthreads();   // vmcnt(0) drain; LDS visible
        s16x8 a[MT][2], b[4][2];
        #pragma unroll
        for (int mt = 0; mt < MT; ++mt)
            #pragma unroll
            for (int kk = 0; kk < 2; ++kk)
                a[mt][kk] = *reinterpret_cast<const s16x8*>(
                    &As[wm + mt * 16 + ln][kk * 32 + quad * 8]);
        #pragma unroll
        for (int nt = 0; nt < 4; ++nt)
            #pragma unroll
            for (int kk = 0; kk < 2; ++kk)
                b[nt][kk] = *reinterpret_cast<const s16x8*>(
                    &Bs[wn + nt * 16 + ln][kk * 32 + quad * 8]);
        #pragma unroll
        for (int kk = 0; kk < 2; ++kk)
            #pragma unroll
            for (int mt = 0; mt < MT; ++mt)
                #pragma unroll
                for (int nt = 0; nt < 4; ++nt)
                    acc[mt][nt] = __builtin_amdgcn_mfma_f32_16x16x32_bf16(
                        a[mt][kk], b[nt][kk], acc[mt][nt], 0, 0, 0);
    }

    float bv[4];
    #pragma unroll
    for (int nt = 0; nt < 4; ++nt) bv[nt] = bias[n0 + wn + nt * 16 + ln];
    #pragma unroll
    for (int mt = 0; mt < MT; ++mt)
        #pragma unroll
        for (int nt = 0; nt < 4; ++nt)
            #pragma unroll
            for (int r = 0; r < 4; ++r) {
                int row = m0 + wm + mt * 16 + quad * 4 + r;
                int col = n0 + wn + nt * 16 + ln;
                float v = acc[mt][nt][r] + bv[nt];
                if (OUT_BF16) ((u16*)Cout)[(size_t)row * N + col] = f2bf(v);
                else          ((float*)Cout)[(size_t)row * N + col] = v;
            }
}

// ---------------- chunk state: G_c = K_c^T @ V_c -> Gt [(c*16+h)][d_v*64+d_k] fp32 ----
__global__ __launch_bounds__(256, 2) void gchunk_kernel(
    const u16* __restrict__ kqvb, float* __restrict__ Gt) {
    __shared__ u16 KT[64][72];   // KT[d_k][t]
    __shared__ u16 VT[64][72];   // VT[d_v][t]
    const int tid = threadIdx.x;
    const int w = tid >> 6, ln = tid & 15, quad = (tid & 63) >> 4;
    const int c = blockIdx.x, h = blockIdx.y;

    #pragma unroll
    for (int l = 0; l < 2; ++l) {
        int idx = tid + 256 * l, t = idx >> 3, dc = (idx & 7) * 8;
        const size_t rb = (size_t)(c * 64 + t) * LD3 + h * DH + dc;
        union { u16 u[8]; f4 v; } pk;
        pk.v = *reinterpret_cast<const f4*>(&kqvb[rb]);            // K
        #pragma unroll
        for (int j = 0; j < 8; ++j) KT[dc + j][t] = pk.u[j];
        pk.v = *reinterpret_cast<const f4*>(&kqvb[rb + 2 * DE]);   // V
        #pragma unroll
        for (int j = 0; j < 8; ++j) VT[dc + j][t] = pk.u[j];
    }
    __syncthreads();

    s16x8 kf[2];
    #pragma unroll
    for (int kk = 0; kk < 2; ++kk)
        kf[kk] = *reinterpret_cast<const s16x8*>(&KT[w * 16 + ln][kk * 32 + quad * 8]);

    f32x4 acc[4];
    #pragma unroll
    for (int nt = 0; nt < 4; ++nt) acc[nt] = 0.f;
    #pragma unroll
    for (int nt = 0; nt < 4; ++nt)
        #pragma unroll
        for (int kk = 0; kk < 2; ++kk) {
            s16x8 vf = *reinterpret_cast<const s16x8*>(&VT[nt * 16 + ln][kk * 32 + quad * 8]);
            acc[nt] = __builtin_amdgcn_mfma_f32_16x16x32_bf16(kf[kk], vf, acc[nt], 0, 0, 0);
        }

    float* base = &Gt[((size_t)(c * 16 + h) << 12)];
    #pragma unroll
    for (int nt = 0; nt < 4; ++nt)
        *reinterpret_cast<f4*>(&base[(nt * 16 + ln) * 64 + w * 16 + quad * 4]) =
            make_float4(acc[nt][0], acc[nt][1], acc[nt][2], acc[nt][3]);
}

// ---------------- exclusive prefix over chunks (fp32), emit bf16 P ----------------
__global__ __launch_bounds__(256) void prefix_scan(
    const float* __restrict__ Gt, u16* __restrict__ P) {
    const int t = blockIdx.x * 256 + threadIdx.x;   // 65536 threads
    const int h = t >> 12, e = t & 4095;
    const size_t stride = (size_t)16 << 12;
    size_t a = ((size_t)h << 12) + e;
    float sum = 0.f;
    float nxt = Gt[a];
    for (int c = 0; c < NCH; ++c) {
        float cur = nxt;
        if (c + 1 < NCH) nxt = Gt[a + stride];   // prefetch next chunk's term
        P[a] = f2bf(sum);
        sum += cur;
        a += stride;
    }
}

// ---------------- intra-chunk causal + inter-chunk Q@P ----------------
__global__ __launch_bounds__(256, 2) void intra_mfma(
    const u16* __restrict__ kqvb, const u16* __restrict__ P,
    u16* __restrict__ attnb) {
    __shared__ u16 VT[64][72];      // VT[d_v][s_local]
    __shared__ u16 Ss[4][16][72];   // per-wave S[q 16][s 64]
    const int tid = threadIdx.x;
    const int w = tid >> 6, ln = tid & 15, quad = (tid & 63) >> 4;
    const int qt = blockIdx.x, h = blockIdx.y;
    const int q0 = qt * 64;

    // cooperative V transpose
    #pragma unroll
    for (int l = 0; l < 2; ++l) {
        int idx = tid + 256 * l, t = idx >> 3, dc = (idx & 7) * 8;
        union { u16 u[8]; f4 v; } pk;
        pk.v = *reinterpret_cast<const f4*>(
            &kqvb[(size_t)(q0 + t) * LD3 + 2 * DE + h * DH + dc]);
        #pragma unroll
        for (int j = 0; j < 8; ++j) VT[dc + j][t] = pk.u[j];
    }

    // Q frags: lane ln <-> q-row (w*16+ln)
    s16x8 qf[2];
    #pragma unroll
    for (int kk = 0; kk < 2; ++kk)
        qf[kk] = *reinterpret_cast<const s16x8*>(
            &kqvb[(size_t)(q0 + w * 16 + ln) * LD3 + DE + h * DH + kk * 32 + quad * 8]);

    // K frags (A-operand, m = s covering the whole 64-row chunk)
    s16x8 kf[4][2];
    #pragma unroll
    for (int mt = 0; mt < 4; ++mt)
        #pragma unroll
        for (int kk = 0; kk < 2; ++kk)
            kf[mt][kk] = *reinterpret_cast<const s16x8*>(
                &kqvb[(size_t)(q0 + mt * 16 + ln) * LD3 + h * DH + kk * 32 + quad * 8]);

    __syncthreads();   // VT ready

    // phase A: S^T = K Q^T, diag mask, pack -> wave-private LDS as S[q][s]
    #pragma unroll
    for (int mt = 0; mt < 4; ++mt) {
        f32x4 s;
        s = 0.f;
        s = __builtin_amdgcn_mfma_f32_16x16x32_bf16(kf[mt][0], qf[0], s, 0, 0, 0);
        s = __builtin_amdgcn_mfma_f32_16x16x32_bf16(kf[mt][1], qf[1], s, 0, 0, 0);
        #pragma unroll
        for (int r = 0; r < 4; ++r)
            if (mt * 16 + quad * 4 + r > w * 16 + ln) s[r] = 0.f;   // s_local > q_local
        __hip_bfloat162 p0 = __float22bfloat162_rn(make_float2(s[0], s[1]));
        __hip_bfloat162 p1 = __float22bfloat162_rn(make_float2(s[2], s[3]));
        uint2 pk = make_uint2(*reinterpret_cast<unsigned int*>(&p0),
                              *reinterpret_cast<unsigned int*>(&p1));
        *reinterpret_cast<uint2*>(&Ss[w][ln][mt * 16 + quad * 4]) = pk;
    }

    s16x8 sf[2];
    #pragma unroll
    for (int kk = 0; kk < 2; ++kk)
        sf[kk] = *reinterpret_cast<const s16x8*>(&Ss[w][ln][kk * 32 + quad * 8]);

    f32x4 accO[4];
    #pragma unroll
    for (int nt = 0; nt < 4; ++nt) accO[nt] = 0.f;

    // phase B: O = S @ V
    #pragma unroll
    for (int nt = 0; nt < 4; ++nt)
        #pragma unroll
        for (int kk = 0; kk < 2; ++kk) {
            s16x8 vf = *reinterpret_cast<const s16x8*>(&VT[nt * 16 + ln][kk * 32 + quad * 8]);
            accO[nt] = __builtin_amdgcn_mfma_f32_16x16x32_bf16(sf[kk], vf, accO[nt], 0, 0, 0);
        }

    // inter-chunk: O += Q @ P
    const u16* Pc = P + (((size_t)(qt * 16 + h)) << 12);
    #pragma unroll
    for (int nt = 0; nt < 4; ++nt)
        #pragma unroll
        for (int kk = 0; kk < 2; ++kk) {
            s16x8 pf = *reinterpret_cast<const s16x8*>(
                &Pc[(nt * 16 + ln) * 64 + kk * 32 + quad * 8]);
            accO[nt] = __builtin_amdgcn_mfma_f32_16x16x32_bf16(qf[kk], pf, accO[nt], 0, 0, 0);
        }

    #pragma unroll
    for (int nt = 0; nt < 4; ++nt)
        #pragma unroll
        for (int r = 0; r < 4; ++r)
            attnb[(size_t)(q0 + w * 16 + quad * 4 + r) * DE + h * DH + nt * 16 + ln] =
                f2bf(accO[nt][r]);
}

extern "C" void kernel_launch(void* const* d_in, const int* in_sizes, int n_in,
                              void* d_out, int out_size, void* d_ws, size_t ws_size,
                              hipStream_t stream) {
    const float* x  = (const float*)d_in[0];
    const float* W1 = (const float*)d_in[1];
    const float* b1 = (const float*)d_in[2];
    const float* W2 = (const float*)d_in[3];
    const float* b2 = (const float*)d_in[4];
    float* out = (float*)d_out;

    u16* xb    = (u16*)d_ws;                       // [4096][1024]; reused as P later
    u16* W1t   = xb    + (size_t)TSEQ * DE;        // [3072][1024]
    u16* W2t   = W1t   + (size_t)LD3 * DE;         // [1024][1024]
    u16* kqvb  = W2t   + (size_t)DE * DE;          // [4096][3072]
    float* Gt  = (float*)(kqvb + (size_t)TSEQ * LD3); // [64ch*16h][4096] fp32 (16.8MB)
    u16* P     = xb;                               // aliases xb (dead after gemm1)
    u16* attnb = (u16*)Gt;                         // aliases Gt (dead after prefix)

    prep_kernel<<<5120, 256, 0, stream>>>(x, W1, W2, xb, W1t, W2t);

    gemm_mfma<128, true><<<dim3(LD3 / 128, TSEQ / 128), 256, 0, stream>>>(
        xb, W1t, b1, kqvb, TSEQ, LD3, DE);

    gchunk_kernel<<<dim3(NCH, NH), 256, 0, stream>>>(kqvb, Gt);
    prefix_scan<<<NH * 4096 / 256, 256, 0, stream>>>(Gt, P);
    intra_mfma<<<dim3(NCH, NH), 256, 0, stream>>>(kqvb, P, attnb);

    gemm_mfma<64, false><<<dim3(DE / 128, TSEQ / 64), 256, 0, stream>>>(
        attnb, W2t, b2, out, TSEQ, DE, DE);
}

// Round 8
// 176.981 us; speedup vs baseline: 1.0370x; 1.0370x over previous
//
#include <hip/hip_runtime.h>
#include <hip/hip_bf16.h>

#define TSEQ 4096
#define DE   1024
#define NH   16
#define DH   64
#define LD3  3072
#define NCH  64          // chunks of 64 rows for the linear-attention scan

typedef float4 f4;
typedef unsigned short u16;
typedef __attribute__((ext_vector_type(8))) short s16x8;   // 8 bf16 MFMA A/B frag
typedef __attribute__((ext_vector_type(4))) float f32x4;   // MFMA C/D frag

__device__ inline u16 f2bf(float f) {
    unsigned int u = __float_as_uint(f);
    u += 0x7FFF + ((u >> 16) & 1);
    return (u16)(u >> 16);
}

__device__ inline void gl_lds16(const void* g, void* l) {
    __builtin_amdgcn_global_load_lds(
        (const __attribute__((address_space(1))) void*)g,
        (__attribute__((address_space(3))) void*)l, 16, 0, 0);
}

// ---------------- fused prep: cast x -> xb; W1 -> W1t; W2 -> W2t ----------------
__global__ __launch_bounds__(256) void prep_kernel(
    const float* __restrict__ x, const float* __restrict__ W1,
    const float* __restrict__ W2, u16* __restrict__ xb,
    u16* __restrict__ W1t, u16* __restrict__ W2t) {
    __shared__ u16 Ts[64][65];
    const int b = blockIdx.x, tid = threadIdx.x;

    if (b < 4096) {   // cast x
        int i = b * 256 + tid;
        f4 v = *reinterpret_cast<const f4*>(&x[(size_t)i * 4]);
        ushort4 o = make_ushort4(f2bf(v.x), f2bf(v.y), f2bf(v.z), f2bf(v.w));
        *reinterpret_cast<ushort4*>(&xb[(size_t)i * 4]) = o;
        return;
    }
    const float* in; u16* out; int in_ld, out_ld, r0, c0;
    if (b < 4864) {
        int i = b - 4096;
        in = W1; out = W1t; in_ld = LD3; out_ld = DE;
        r0 = (i / 48) * 64; c0 = (i % 48) * 64;
    } else {
        int i = b - 4864;
        in = W2; out = W2t; in_ld = DE; out_ld = DE;
        r0 = (i / 16) * 64; c0 = (i % 16) * 64;
    }
    #pragma unroll
    for (int l = 0; l < 4; ++l) {
        int f = tid + 256 * l, r = f >> 4, c = (f & 15) * 4;
        f4 v = *reinterpret_cast<const f4*>(&in[(size_t)(r0 + r) * in_ld + c0 + c]);
        Ts[c + 0][r] = f2bf(v.x); Ts[c + 1][r] = f2bf(v.y);
        Ts[c + 2][r] = f2bf(v.z); Ts[c + 3][r] = f2bf(v.w);
    }
    __syncthreads();
    #pragma unroll
    for (int l = 0; l < 2; ++l) {
        int f = tid + 256 * l, r2 = f >> 3, c2 = (f & 7) * 8;
        union { u16 u[8]; f4 v; } pk;
        #pragma unroll
        for (int j = 0; j < 8; ++j) pk.u[j] = Ts[r2][c2 + j];
        *reinterpret_cast<f4*>(&out[(size_t)(c0 + r2) * out_ld + r0 + c2]) = pk.v;
    }
}

// ---------------- bf16 MFMA GEMM: 2x [.][32] LDS buffers, one barrier pair / 64 K ----
// C[M][N] = A[M][K] @ Bt[N][K]^T + bias. 256 threads, 4 waves 2x2, wave tile (TM/2)x64.
// Row stride stays 32 u16 = 64 B = 16 banks (2-way aliasing, free); BK=64 via two
// independent 32-wide buffers -> half the barrier pairs of R6 at R6's bank layout.
// k ascending across s=0,1 -> bit-identical accumulation to R6.
template<int TM, bool OUT_BF16>
__global__ __launch_bounds__(256) void gemm_mfma(
    const u16* __restrict__ A, const u16* __restrict__ Bt,
    const float* __restrict__ bias, void* __restrict__ Cout,
    int M, int N, int K) {
    constexpr int MT = TM / 32;          // m sub-tiles (16 rows) per wave
    __shared__ u16 As[2][TM][32];
    __shared__ u16 Bs[2][128][32];
    const int tid = threadIdx.x;
    const int m0 = blockIdx.y * TM, n0 = blockIdx.x * 128;
    const int w = tid >> 6, lid = tid & 63, ln = tid & 15, quad = (tid & 63) >> 4;
    const int wm = (w >> 1) * (TM / 2), wn = (w & 1) * 64;
    const int srow = lid >> 2, scol = (lid & 3) * 8;   // lane's slot in a 16-row chunk

    f32x4 acc[MT][4];
    #pragma unroll
    for (int i = 0; i < MT; ++i)
        #pragma unroll
        for (int j = 0; j < 4; ++j) acc[i][j] = 0.f;

    for (int k0 = 0; k0 < K; k0 += 64) {
        __syncthreads();   // previous iteration's readers done
        #pragma unroll
        for (int s = 0; s < 2; ++s) {
            const int kb = k0 + s * 32;
            #pragma unroll
            for (int i = 0; i < TM / 64; ++i) {
                const int rb = w * 16 + i * 64;
                gl_lds16(&A[(size_t)(m0 + rb + srow) * K + kb + scol], &As[s][rb][0]);
            }
            #pragma unroll
            for (int i = 0; i < 2; ++i) {
                const int rb = w * 16 + i * 64;
                gl_lds16(&Bt[(size_t)(n0 + rb + srow) * K + kb + scol], &Bs[s][rb][0]);
            }
        }
        __syncthreads();   // vmcnt(0) drain; LDS visible
        #pragma unroll
        for (int s = 0; s < 2; ++s) {
            s16x8 a[MT], b[4];
            #pragma unroll
            for (int mt = 0; mt < MT; ++mt)
                a[mt] = *reinterpret_cast<const s16x8*>(&As[s][wm + mt * 16 + ln][quad * 8]);
            #pragma unroll
            for (int nt = 0; nt < 4; ++nt)
                b[nt] = *reinterpret_cast<const s16x8*>(&Bs[s][wn + nt * 16 + ln][quad * 8]);
            #pragma unroll
            for (int mt = 0; mt < MT; ++mt)
                #pragma unroll
                for (int nt = 0; nt < 4; ++nt)
                    acc[mt][nt] = __builtin_amdgcn_mfma_f32_16x16x32_bf16(
                        a[mt], b[nt], acc[mt][nt], 0, 0, 0);
        }
    }

    float bv[4];
    #pragma unroll
    for (int nt = 0; nt < 4; ++nt) bv[nt] = bias[n0 + wn + nt * 16 + ln];
    #pragma unroll
    for (int mt = 0; mt < MT; ++mt)
        #pragma unroll
        for (int nt = 0; nt < 4; ++nt)
            #pragma unroll
            for (int r = 0; r < 4; ++r) {
                int row = m0 + wm + mt * 16 + quad * 4 + r;
                int col = n0 + wn + nt * 16 + ln;
                float v = acc[mt][nt][r] + bv[nt];
                if (OUT_BF16) ((u16*)Cout)[(size_t)row * N + col] = f2bf(v);
                else          ((float*)Cout)[(size_t)row * N + col] = v;
            }
}

// ---------------- chunk state: G_c = K_c^T @ V_c -> Gt [(c*16+h)][d_v*64+d_k] fp32 ----
__global__ __launch_bounds__(256, 2) void gchunk_kernel(
    const u16* __restrict__ kqvb, float* __restrict__ Gt) {
    __shared__ u16 KT[64][72];   // KT[d_k][t]
    __shared__ u16 VT[64][72];   // VT[d_v][t]
    const int tid = threadIdx.x;
    const int w = tid >> 6, ln = tid & 15, quad = (tid & 63) >> 4;
    const int c = blockIdx.x, h = blockIdx.y;

    #pragma unroll
    for (int l = 0; l < 2; ++l) {
        int idx = tid + 256 * l, t = idx >> 3, dc = (idx & 7) * 8;
        const size_t rb = (size_t)(c * 64 + t) * LD3 + h * DH + dc;
        union { u16 u[8]; f4 v; } pk;
        pk.v = *reinterpret_cast<const f4*>(&kqvb[rb]);            // K
        #pragma unroll
        for (int j = 0; j < 8; ++j) KT[dc + j][t] = pk.u[j];
        pk.v = *reinterpret_cast<const f4*>(&kqvb[rb + 2 * DE]);   // V
        #pragma unroll
        for (int j = 0; j < 8; ++j) VT[dc + j][t] = pk.u[j];
    }
    __syncthreads();

    s16x8 kf[2];
    #pragma unroll
    for (int kk = 0; kk < 2; ++kk)
        kf[kk] = *reinterpret_cast<const s16x8*>(&KT[w * 16 + ln][kk * 32 + quad * 8]);

    f32x4 acc[4];
    #pragma unroll
    for (int nt = 0; nt < 4; ++nt) acc[nt] = 0.f;
    #pragma unroll
    for (int nt = 0; nt < 4; ++nt)
        #pragma unroll
        for (int kk = 0; kk < 2; ++kk) {
            s16x8 vf = *reinterpret_cast<const s16x8*>(&VT[nt * 16 + ln][kk * 32 + quad * 8]);
            acc[nt] = __builtin_amdgcn_mfma_f32_16x16x32_bf16(kf[kk], vf, acc[nt], 0, 0, 0);
        }

    float* base = &Gt[((size_t)(c * 16 + h) << 12)];
    #pragma unroll
    for (int nt = 0; nt < 4; ++nt)
        *reinterpret_cast<f4*>(&base[(nt * 16 + ln) * 64 + w * 16 + quad * 4]) =
            make_float4(acc[nt][0], acc[nt][1], acc[nt][2], acc[nt][3]);
}

// ---------------- exclusive prefix over chunks (fp32), emit bf16 P ----------------
__global__ __launch_bounds__(256) void prefix_scan(
    const float* __restrict__ Gt, u16* __restrict__ P) {
    const int t = blockIdx.x * 256 + threadIdx.x;   // 65536 threads
    const int h = t >> 12, e = t & 4095;
    const size_t stride = (size_t)16 << 12;
    size_t a = ((size_t)h << 12) + e;
    float sum = 0.f;
    float nxt = Gt[a];
    for (int c = 0; c < NCH; ++c) {
        float cur = nxt;
        if (c + 1 < NCH) nxt = Gt[a + stride];   // prefetch next chunk's term
        P[a] = f2bf(sum);
        sum += cur;
        a += stride;
    }
}

// ---------------- intra-chunk causal + inter-chunk Q@P ----------------
__global__ __launch_bounds__(256, 2) void intra_mfma(
    const u16* __restrict__ kqvb, const u16* __restrict__ P,
    u16* __restrict__ attnb) {
    __shared__ u16 VT[64][72];      // VT[d_v][s_local]
    __shared__ u16 Ss[4][16][72];   // per-wave S[q 16][s 64]
    const int tid = threadIdx.x;
    const int w = tid >> 6, ln = tid & 15, quad = (tid & 63) >> 4;
    const int qt = blockIdx.x, h = blockIdx.y;
    const int q0 = qt * 64;

    // cooperative V transpose
    #pragma unroll
    for (int l = 0; l < 2; ++l) {
        int idx = tid + 256 * l, t = idx >> 3, dc = (idx & 7) * 8;
        union { u16 u[8]; f4 v; } pk;
        pk.v = *reinterpret_cast<const f4*>(
            &kqvb[(size_t)(q0 + t) * LD3 + 2 * DE + h * DH + dc]);
        #pragma unroll
        for (int j = 0; j < 8; ++j) VT[dc + j][t] = pk.u[j];
    }

    // Q frags: lane ln <-> q-row (w*16+ln)
    s16x8 qf[2];
    #pragma unroll
    for (int kk = 0; kk < 2; ++kk)
        qf[kk] = *reinterpret_cast<const s16x8*>(
            &kqvb[(size_t)(q0 + w * 16 + ln) * LD3 + DE + h * DH + kk * 32 + quad * 8]);

    // K frags (A-operand, m = s covering the whole 64-row chunk)
    s16x8 kf[4][2];
    #pragma unroll
    for (int mt = 0; mt < 4; ++mt)
        #pragma unroll
        for (int kk = 0; kk < 2; ++kk)
            kf[mt][kk] = *reinterpret_cast<const s16x8*>(
                &kqvb[(size_t)(q0 + mt * 16 + ln) * LD3 + h * DH + kk * 32 + quad * 8]);

    __syncthreads();   // VT ready

    // phase A: S^T = K Q^T, diag mask, pack -> wave-private LDS as S[q][s]
    #pragma unroll
    for (int mt = 0; mt < 4; ++mt) {
        f32x4 s;
        s = 0.f;
        s = __builtin_amdgcn_mfma_f32_16x16x32_bf16(kf[mt][0], qf[0], s, 0, 0, 0);
        s = __builtin_amdgcn_mfma_f32_16x16x32_bf16(kf[mt][1], qf[1], s, 0, 0, 0);
        #pragma unroll
        for (int r = 0; r < 4; ++r)
            if (mt * 16 + quad * 4 + r > w * 16 + ln) s[r] = 0.f;   // s_local > q_local
        __hip_bfloat162 p0 = __float22bfloat162_rn(make_float2(s[0], s[1]));
        __hip_bfloat162 p1 = __float22bfloat162_rn(make_float2(s[2], s[3]));
        uint2 pk = make_uint2(*reinterpret_cast<unsigned int*>(&p0),
                              *reinterpret_cast<unsigned int*>(&p1));
        *reinterpret_cast<uint2*>(&Ss[w][ln][mt * 16 + quad * 4]) = pk;
    }

    s16x8 sf[2];
    #pragma unroll
    for (int kk = 0; kk < 2; ++kk)
        sf[kk] = *reinterpret_cast<const s16x8*>(&Ss[w][ln][kk * 32 + quad * 8]);

    f32x4 accO[4];
    #pragma unroll
    for (int nt = 0; nt < 4; ++nt) accO[nt] = 0.f;

    // phase B: O = S @ V
    #pragma unroll
    for (int nt = 0; nt < 4; ++nt)
        #pragma unroll
        for (int kk = 0; kk < 2; ++kk) {
            s16x8 vf = *reinterpret_cast<const s16x8*>(&VT[nt * 16 + ln][kk * 32 + quad * 8]);
            accO[nt] = __builtin_amdgcn_mfma_f32_16x16x32_bf16(sf[kk], vf, accO[nt], 0, 0, 0);
        }

    // inter-chunk: O += Q @ P
    const u16* Pc = P + (((size_t)(qt * 16 + h)) << 12);
    #pragma unroll
    for (int nt = 0; nt < 4; ++nt)
        #pragma unroll
        for (int kk = 0; kk < 2; ++kk) {
            s16x8 pf = *reinterpret_cast<const s16x8*>(
                &Pc[(nt * 16 + ln) * 64 + kk * 32 + quad * 8]);
            accO[nt] = __builtin_amdgcn_mfma_f32_16x16x32_bf16(qf[kk], pf, accO[nt], 0, 0, 0);
        }

    #pragma unroll
    for (int nt = 0; nt < 4; ++nt)
        #pragma unroll
        for (int r = 0; r < 4; ++r)
            attnb[(size_t)(q0 + w * 16 + quad * 4 + r) * DE + h * DH + nt * 16 + ln] =
                f2bf(accO[nt][r]);
}

extern "C" void kernel_launch(void* const* d_in, const int* in_sizes, int n_in,
                              void* d_out, int out_size, void* d_ws, size_t ws_size,
                              hipStream_t stream) {
    const float* x  = (const float*)d_in[0];
    const float* W1 = (const float*)d_in[1];
    const float* b1 = (const float*)d_in[2];
    const float* W2 = (const float*)d_in[3];
    const float* b2 = (const float*)d_in[4];
    float* out = (float*)d_out;

    u16* xb    = (u16*)d_ws;                       // [4096][1024]; reused as P later
    u16* W1t   = xb    + (size_t)TSEQ * DE;        // [3072][1024]
    u16* W2t   = W1t   + (size_t)LD3 * DE;         // [1024][1024]
    u16* kqvb  = W2t   + (size_t)DE * DE;          // [4096][3072]
    float* Gt  = (float*)(kqvb + (size_t)TSEQ * LD3); // [64ch*16h][4096] fp32 (16.8MB)
    u16* P     = xb;                               // aliases xb (dead after gemm1)
    u16* attnb = (u16*)Gt;                         // aliases Gt (dead after prefix)

    prep_kernel<<<5120, 256, 0, stream>>>(x, W1, W2, xb, W1t, W2t);

    gemm_mfma<128, true><<<dim3(LD3 / 128, TSEQ / 128), 256, 0, stream>>>(
        xb, W1t, b1, kqvb, TSEQ, LD3, DE);

    gchunk_kernel<<<dim3(NCH, NH), 256, 0, stream>>>(kqvb, Gt);
    prefix_scan<<<NH * 4096 / 256, 256, 0, stream>>>(Gt, P);
    intra_mfma<<<dim3(NCH, NH), 256, 0, stream>>>(kqvb, P, attnb);

    gemm_mfma<64, false><<<dim3(DE / 128, TSEQ / 64), 256, 0, stream>>>(
        attnb, W2t, b2, out, TSEQ, DE, DE);
}

// Round 9
// 169.545 us; speedup vs baseline: 1.0825x; 1.0439x over previous
//
#include <hip/hip_runtime.h>
#include <hip/hip_bf16.h>

#define TSEQ 4096
#define DE   1024
#define NH   16
#define DH   64
#define LD3  3072
#define NCH  64          // chunks of 64 rows for the linear-attention scan

typedef float4 f4;
typedef unsigned short u16;
typedef __attribute__((ext_vector_type(8))) short s16x8;   // 8 bf16 MFMA A/B frag
typedef __attribute__((ext_vector_type(4))) float f32x4;   // MFMA C/D frag

__device__ inline u16 f2bf(float f) {
    unsigned int u = __float_as_uint(f);
    u += 0x7FFF + ((u >> 16) & 1);
    return (u16)(u >> 16);
}

__device__ inline void gl_lds16(const void* g, void* l) {
    __builtin_amdgcn_global_load_lds(
        (const __attribute__((address_space(1))) void*)g,
        (__attribute__((address_space(3))) void*)l, 16, 0, 0);
}

// ---------------- fused prep: cast x -> xb; W1 -> W1t; W2 -> W2t ----------------
__global__ __launch_bounds__(256) void prep_kernel(
    const float* __restrict__ x, const float* __restrict__ W1,
    const float* __restrict__ W2, u16* __restrict__ xb,
    u16* __restrict__ W1t, u16* __restrict__ W2t) {
    __shared__ u16 Ts[64][65];
    const int b = blockIdx.x, tid = threadIdx.x;

    if (b < 4096) {   // cast x
        int i = b * 256 + tid;
        f4 v = *reinterpret_cast<const f4*>(&x[(size_t)i * 4]);
        ushort4 o = make_ushort4(f2bf(v.x), f2bf(v.y), f2bf(v.z), f2bf(v.w));
        *reinterpret_cast<ushort4*>(&xb[(size_t)i * 4]) = o;
        return;
    }
    const float* in; u16* out; int in_ld, out_ld, r0, c0;
    if (b < 4864) {
        int i = b - 4096;
        in = W1; out = W1t; in_ld = LD3; out_ld = DE;
        r0 = (i / 48) * 64; c0 = (i % 48) * 64;
    } else {
        int i = b - 4864;
        in = W2; out = W2t; in_ld = DE; out_ld = DE;
        r0 = (i / 16) * 64; c0 = (i % 16) * 64;
    }
    #pragma unroll
    for (int l = 0; l < 4; ++l) {
        int f = tid + 256 * l, r = f >> 4, c = (f & 15) * 4;
        f4 v = *reinterpret_cast<const f4*>(&in[(size_t)(r0 + r) * in_ld + c0 + c]);
        Ts[c + 0][r] = f2bf(v.x); Ts[c + 1][r] = f2bf(v.y);
        Ts[c + 2][r] = f2bf(v.z); Ts[c + 3][r] = f2bf(v.w);
    }
    __syncthreads();
    #pragma unroll
    for (int l = 0; l < 2; ++l) {
        int f = tid + 256 * l, r2 = f >> 3, c2 = (f & 7) * 8;
        union { u16 u[8]; f4 v; } pk;
        #pragma unroll
        for (int j = 0; j < 8; ++j) pk.u[j] = Ts[r2][c2 + j];
        *reinterpret_cast<f4*>(&out[(size_t)(c0 + r2) * out_ld + r0 + c2]) = pk.v;
    }
}

// ---------------- bf16 MFMA GEMM, BK=32, [.][32] LDS (R6 config — best measured) ----
// C[M][N] = A[M][K] @ Bt[N][K]^T + bias. 256 threads, 4 waves 2x2, wave tile (TM/2)x64.
// 16 KB (TM=128) / 12 KB (TM=64) LDS -> high residency; row stride 64 B (2-way banks, free).
template<int TM, bool OUT_BF16>
__global__ __launch_bounds__(256) void gemm_mfma(
    const u16* __restrict__ A, const u16* __restrict__ Bt,
    const float* __restrict__ bias, void* __restrict__ Cout,
    int M, int N, int K) {
    constexpr int MT = TM / 32;          // m sub-tiles (16 rows) per wave
    __shared__ u16 As[TM][32];
    __shared__ u16 Bs[128][32];
    const int tid = threadIdx.x;
    const int m0 = blockIdx.y * TM, n0 = blockIdx.x * 128;
    const int w = tid >> 6, lid = tid & 63, ln = tid & 15, quad = (tid & 63) >> 4;
    const int wm = (w >> 1) * (TM / 2), wn = (w & 1) * 64;
    const int srow = lid >> 2, scol = (lid & 3) * 8;   // lane's slot in a 16-row chunk

    f32x4 acc[MT][4];
    #pragma unroll
    for (int i = 0; i < MT; ++i)
        #pragma unroll
        for (int j = 0; j < 4; ++j) acc[i][j] = 0.f;

    for (int k0 = 0; k0 < K; k0 += 32) {
        __syncthreads();   // previous iteration's readers done
        #pragma unroll
        for (int i = 0; i < TM / 64; ++i) {
            const int rb = w * 16 + i * 64;
            gl_lds16(&A[(size_t)(m0 + rb + srow) * K + k0 + scol], &As[rb][0]);
        }
        #pragma unroll
        for (int i = 0; i < 2; ++i) {
            const int rb = w * 16 + i * 64;
            gl_lds16(&Bt[(size_t)(n0 + rb + srow) * K + k0 + scol], &Bs[rb][0]);
        }
        __syncthreads();   // vmcnt(0) drain; LDS visible
        s16x8 a[MT], b[4];
        #pragma unroll
        for (int mt = 0; mt < MT; ++mt)
            a[mt] = *reinterpret_cast<const s16x8*>(&As[wm + mt * 16 + ln][quad * 8]);
        #pragma unroll
        for (int nt = 0; nt < 4; ++nt)
            b[nt] = *reinterpret_cast<const s16x8*>(&Bs[wn + nt * 16 + ln][quad * 8]);
        #pragma unroll
        for (int mt = 0; mt < MT; ++mt)
            #pragma unroll
            for (int nt = 0; nt < 4; ++nt)
                acc[mt][nt] = __builtin_amdgcn_mfma_f32_16x16x32_bf16(
                    a[mt], b[nt], acc[mt][nt], 0, 0, 0);
    }

    float bv[4];
    #pragma unroll
    for (int nt = 0; nt < 4; ++nt) bv[nt] = bias[n0 + wn + nt * 16 + ln];
    #pragma unroll
    for (int mt = 0; mt < MT; ++mt)
        #pragma unroll
        for (int nt = 0; nt < 4; ++nt)
            #pragma unroll
            for (int r = 0; r < 4; ++r) {
                int row = m0 + wm + mt * 16 + quad * 4 + r;
                int col = n0 + wn + nt * 16 + ln;
                float v = acc[mt][nt][r] + bv[nt];
                if (OUT_BF16) ((u16*)Cout)[(size_t)row * N + col] = f2bf(v);
                else          ((float*)Cout)[(size_t)row * N + col] = v;
            }
}

// ---------------- chunk state: G_c = K_c^T @ V_c -> Gt [(c*16+h)][d_v*64+d_k] fp32 ----
__global__ __launch_bounds__(256, 2) void gchunk_kernel(
    const u16* __restrict__ kqvb, float* __restrict__ Gt) {
    __shared__ u16 KT[64][72];   // KT[d_k][t]
    __shared__ u16 VT[64][72];   // VT[d_v][t]
    const int tid = threadIdx.x;
    const int w = tid >> 6, ln = tid & 15, quad = (tid & 63) >> 4;
    const int c = blockIdx.x, h = blockIdx.y;

    #pragma unroll
    for (int l = 0; l < 2; ++l) {
        int idx = tid + 256 * l, t = idx >> 3, dc = (idx & 7) * 8;
        const size_t rb = (size_t)(c * 64 + t) * LD3 + h * DH + dc;
        union { u16 u[8]; f4 v; } pk;
        pk.v = *reinterpret_cast<const f4*>(&kqvb[rb]);            // K
        #pragma unroll
        for (int j = 0; j < 8; ++j) KT[dc + j][t] = pk.u[j];
        pk.v = *reinterpret_cast<const f4*>(&kqvb[rb + 2 * DE]);   // V
        #pragma unroll
        for (int j = 0; j < 8; ++j) VT[dc + j][t] = pk.u[j];
    }
    __syncthreads();

    s16x8 kf[2];
    #pragma unroll
    for (int kk = 0; kk < 2; ++kk)
        kf[kk] = *reinterpret_cast<const s16x8*>(&KT[w * 16 + ln][kk * 32 + quad * 8]);

    f32x4 acc[4];
    #pragma unroll
    for (int nt = 0; nt < 4; ++nt) acc[nt] = 0.f;
    #pragma unroll
    for (int nt = 0; nt < 4; ++nt)
        #pragma unroll
        for (int kk = 0; kk < 2; ++kk) {
            s16x8 vf = *reinterpret_cast<const s16x8*>(&VT[nt * 16 + ln][kk * 32 + quad * 8]);
            acc[nt] = __builtin_amdgcn_mfma_f32_16x16x32_bf16(kf[kk], vf, acc[nt], 0, 0, 0);
        }

    float* base = &Gt[((size_t)(c * 16 + h) << 12)];
    #pragma unroll
    for (int nt = 0; nt < 4; ++nt)
        *reinterpret_cast<f4*>(&base[(nt * 16 + ln) * 64 + w * 16 + quad * 4]) =
            make_float4(acc[nt][0], acc[nt][1], acc[nt][2], acc[nt][3]);
}

// ---------------- exclusive prefix over chunks (fp32), emit bf16 P ----------------
__global__ __launch_bounds__(256) void prefix_scan(
    const float* __restrict__ Gt, u16* __restrict__ P) {
    const int t = blockIdx.x * 256 + threadIdx.x;   // 65536 threads
    const int h = t >> 12, e = t & 4095;
    const size_t stride = (size_t)16 << 12;
    size_t a = ((size_t)h << 12) + e;
    float sum = 0.f;
    float nxt = Gt[a];
    for (int c = 0; c < NCH; ++c) {
        float cur = nxt;
        if (c + 1 < NCH) nxt = Gt[a + stride];   // prefetch next chunk's term
        P[a] = f2bf(sum);
        sum += cur;
        a += stride;
    }
}

// ---------------- intra-chunk causal + inter-chunk Q@P ----------------
__global__ __launch_bounds__(256, 2) void intra_mfma(
    const u16* __restrict__ kqvb, const u16* __restrict__ P,
    u16* __restrict__ attnb) {
    __shared__ u16 VT[64][72];      // VT[d_v][s_local]
    __shared__ u16 Ss[4][16][72];   // per-wave S[q 16][s 64]
    const int tid = threadIdx.x;
    const int w = tid >> 6, ln = tid & 15, quad = (tid & 63) >> 4;
    const int qt = blockIdx.x, h = blockIdx.y;
    const int q0 = qt * 64;

    // cooperative V transpose
    #pragma unroll
    for (int l = 0; l < 2; ++l) {
        int idx = tid + 256 * l, t = idx >> 3, dc = (idx & 7) * 8;
        union { u16 u[8]; f4 v; } pk;
        pk.v = *reinterpret_cast<const f4*>(
            &kqvb[(size_t)(q0 + t) * LD3 + 2 * DE + h * DH + dc]);
        #pragma unroll
        for (int j = 0; j < 8; ++j) VT[dc + j][t] = pk.u[j];
    }

    // Q frags: lane ln <-> q-row (w*16+ln)
    s16x8 qf[2];
    #pragma unroll
    for (int kk = 0; kk < 2; ++kk)
        qf[kk] = *reinterpret_cast<const s16x8*>(
            &kqvb[(size_t)(q0 + w * 16 + ln) * LD3 + DE + h * DH + kk * 32 + quad * 8]);

    // K frags (A-operand, m = s covering the whole 64-row chunk)
    s16x8 kf[4][2];
    #pragma unroll
    for (int mt = 0; mt < 4; ++mt)
        #pragma unroll
        for (int kk = 0; kk < 2; ++kk)
            kf[mt][kk] = *reinterpret_cast<const s16x8*>(
                &kqvb[(size_t)(q0 + mt * 16 + ln) * LD3 + h * DH + kk * 32 + quad * 8]);

    __syncthreads();   // VT ready

    // phase A: S^T = K Q^T, diag mask, pack -> wave-private LDS as S[q][s]
    #pragma unroll
    for (int mt = 0; mt < 4; ++mt) {
        f32x4 s;
        s = 0.f;
        s = __builtin_amdgcn_mfma_f32_16x16x32_bf16(kf[mt][0], qf[0], s, 0, 0, 0);
        s = __builtin_amdgcn_mfma_f32_16x16x32_bf16(kf[mt][1], qf[1], s, 0, 0, 0);
        #pragma unroll
        for (int r = 0; r < 4; ++r)
            if (mt * 16 + quad * 4 + r > w * 16 + ln) s[r] = 0.f;   // s_local > q_local
        __hip_bfloat162 p0 = __float22bfloat162_rn(make_float2(s[0], s[1]));
        __hip_bfloat162 p1 = __float22bfloat162_rn(make_float2(s[2], s[3]));
        uint2 pk = make_uint2(*reinterpret_cast<unsigned int*>(&p0),
                              *reinterpret_cast<unsigned int*>(&p1));
        *reinterpret_cast<uint2*>(&Ss[w][ln][mt * 16 + quad * 4]) = pk;
    }

    s16x8 sf[2];
    #pragma unroll
    for (int kk = 0; kk < 2; ++kk)
        sf[kk] = *reinterpret_cast<const s16x8*>(&Ss[w][ln][kk * 32 + quad * 8]);

    f32x4 accO[4];
    #pragma unroll
    for (int nt = 0; nt < 4; ++nt) accO[nt] = 0.f;

    // phase B: O = S @ V
    #pragma unroll
    for (int nt = 0; nt < 4; ++nt)
        #pragma unroll
        for (int kk = 0; kk < 2; ++kk) {
            s16x8 vf = *reinterpret_cast<const s16x8*>(&VT[nt * 16 + ln][kk * 32 + quad * 8]);
            accO[nt] = __builtin_amdgcn_mfma_f32_16x16x32_bf16(sf[kk], vf, accO[nt], 0, 0, 0);
        }

    // inter-chunk: O += Q @ P
    const u16* Pc = P + (((size_t)(qt * 16 + h)) << 12);
    #pragma unroll
    for (int nt = 0; nt < 4; ++nt)
        #pragma unroll
        for (int kk = 0; kk < 2; ++kk) {
            s16x8 pf = *reinterpret_cast<const s16x8*>(
                &Pc[(nt * 16 + ln) * 64 + kk * 32 + quad * 8]);
            accO[nt] = __builtin_amdgcn_mfma_f32_16x16x32_bf16(qf[kk], pf, accO[nt], 0, 0, 0);
        }

    #pragma unroll
    for (int nt = 0; nt < 4; ++nt)
        #pragma unroll
        for (int r = 0; r < 4; ++r)
            attnb[(size_t)(q0 + w * 16 + quad * 4 + r) * DE + h * DH + nt * 16 + ln] =
                f2bf(accO[nt][r]);
}

extern "C" void kernel_launch(void* const* d_in, const int* in_sizes, int n_in,
                              void* d_out, int out_size, void* d_ws, size_t ws_size,
                              hipStream_t stream) {
    const float* x  = (const float*)d_in[0];
    const float* W1 = (const float*)d_in[1];
    const float* b1 = (const float*)d_in[2];
    const float* W2 = (const float*)d_in[3];
    const float* b2 = (const float*)d_in[4];
    float* out = (float*)d_out;

    u16* xb    = (u16*)d_ws;                       // [4096][1024]; reused as P later
    u16* W1t   = xb    + (size_t)TSEQ * DE;        // [3072][1024]
    u16* W2t   = W1t   + (size_t)LD3 * DE;         // [1024][1024]
    u16* kqvb  = W2t   + (size_t)DE * DE;          // [4096][3072]
    float* Gt  = (float*)(kqvb + (size_t)TSEQ * LD3); // [64ch*16h][4096] fp32 (16.8MB)
    u16* P     = xb;                               // aliases xb (dead after gemm1)
    u16* attnb = (u16*)Gt;                         // aliases Gt (dead after prefix)

    prep_kernel<<<5120, 256, 0, stream>>>(x, W1, W2, xb, W1t, W2t);

    gemm_mfma<128, true><<<dim3(LD3 / 128, TSEQ / 128), 256, 0, stream>>>(
        xb, W1t, b1, kqvb, TSEQ, LD3, DE);

    gchunk_kernel<<<dim3(NCH, NH), 256, 0, stream>>>(kqvb, Gt);
    prefix_scan<<<NH * 4096 / 256, 256, 0, stream>>>(Gt, P);
    intra_mfma<<<dim3(NCH, NH), 256, 0, stream>>>(kqvb, P, attnb);

    gemm_mfma<64, false><<<dim3(DE / 128, TSEQ / 64), 256, 0, stream>>>(
        attnb, W2t, b2, out, TSEQ, DE, DE);
}